// Round 7
// baseline (514.546 us; speedup 1.0000x reference)
//
#include <hip/hip_runtime.h>
#include <math.h>

#define NN 20000
#define NN_PAD 20096   // NN rounded up to TM; pad rows are garbage, never stored
#define EE 320000
#define RR 3
#define LL 3
#define HH 4
#define DD 64
#define CDIM 256   // H*D == IN
#define OUTD 128
#define NEG 0.2f

#define CVT_N4 (NN * CDIM / 4)             // 1,280,000 float4 groups
#define CVT_BLK ((CVT_N4 + 255) / 256)     // 5000
#define CNT_BLK ((RR * EE + 255) / 256)    // 3750
#define PREP_BLK (8 * 8 * (LL * RR + 1))   // 640

typedef float f32x4 __attribute__((ext_vector_type(4)));
typedef short sh8 __attribute__((ext_vector_type(8)));

__device__ __forceinline__ ushort f2bf(float f) {
    union { float f; uint u; } v; v.f = f;
    uint r = (v.u + 0x7FFF + ((v.u >> 16) & 1)) >> 16;   // RNE
    return (ushort)r;
}
__device__ __forceinline__ float bf2f(ushort u) {
    union { uint u; float f; } v; v.u = ((uint)u) << 16;
    return v.f;
}
__device__ __forceinline__ float bflo(uint p) { return bf2f((ushort)(p & 0xffff)); }
__device__ __forceinline__ float bfhi(uint p) { return bf2f((ushort)(p >> 16)); }

// async global->LDS, 16 B per lane; LDS dst is wave-uniform base + lane*16
__device__ __forceinline__ void glds16(const ushort* g, ushort* l) {
    __builtin_amdgcn_global_load_lds(
        (const __attribute__((address_space(1))) void*)g,
        (__attribute__((address_space(3))) void*)l, 16, 0, 0);
}

// ---------------- fused prologue 1: x->bf16 cvt  ||  degree count ----------------
__global__ __launch_bounds__(256) void fused_cvt_count(
    const float* __restrict__ in, ushort* __restrict__ out,
    const int* __restrict__ edge_dst, int* __restrict__ deg) {
    int bid = blockIdx.x;
    if (bid < CVT_BLK) {
        int i = bid * 256 + threadIdx.x;
        if (i >= CVT_N4) return;
        float4 v = *(const float4*)(in + (size_t)i * 4);
        ushort4 o;
        o.x = f2bf(v.x); o.y = f2bf(v.y); o.z = f2bf(v.z); o.w = f2bf(v.w);
        *(ushort4*)(out + (size_t)i * 4) = o;
    } else {
        int i = (bid - CVT_BLK) * 256 + threadIdx.x;
        if (i >= RR * EE) return;
        int r = i / EE;
        atomicAdd(&deg[r * NN + edge_dst[i]], 1);
    }
}

// one block per relation; wave-shfl scan; writes row_ptr AND cursor copy.
__global__ __launch_bounds__(1024) void scan_kernel(
    const int* __restrict__ deg, int* __restrict__ row_ptr, int* __restrict__ cursor) {
    int r = blockIdx.x;
    const int* d = deg + r * NN;
    int* rp = row_ptr + r * (NN + 1);
    int* cur = cursor + r * (NN + 1);
    __shared__ int wsum[16];
    int lane = threadIdx.x & 63, wv = threadIdx.x >> 6;
    if (threadIdx.x == 0) { rp[0] = 0; cur[0] = 0; }
    int carry = 0;
    for (int base = 0; base < NN; base += 1024) {
        int i = base + threadIdx.x;
        int v = (i < NN) ? d[i] : 0;
        int s = v;
        #pragma unroll
        for (int off = 1; off < 64; off <<= 1) {
            int n = __shfl_up(s, off, 64);
            if (lane >= off) s += n;
        }
        if (lane == 63) wsum[wv] = s;
        __syncthreads();
        if (wv == 0) {
            int ws = (lane < 16) ? wsum[lane] : 0;
            #pragma unroll
            for (int off = 1; off < 16; off <<= 1) {
                int n = __shfl_up(ws, off, 64);
                if (lane >= off) ws += n;
            }
            if (lane < 16) wsum[lane] = ws;
        }
        __syncthreads();
        int incl = carry + (wv ? wsum[wv - 1] : 0) + s;
        if (i < NN) { rp[i + 1] = incl; cur[i + 1] = incl; }
        carry += wsum[15];
        __syncthreads();
    }
}

// ---------------- fused prologue 2: CSR fill  ||  weight transpose prep ----------------
__global__ __launch_bounds__(256) void fused_fill_prep(
    const int* __restrict__ edge_src, const int* __restrict__ edge_dst,
    int* __restrict__ cursor, int* __restrict__ csr_src,
    const float* __restrict__ W, const float* __restrict__ fc_w,
    ushort* __restrict__ Wt, ushort* __restrict__ fct) {
    __shared__ float tile[32][33];
    int bid = blockIdx.x;
    if (bid < CNT_BLK) {
        int i = bid * 256 + threadIdx.x;
        if (i >= RR * EE) return;
        int r = i / EE;
        int dst = edge_dst[i];
        int pos = atomicAdd(&cursor[r * (NN + 1) + dst], 1);
        csr_src[r * EE + pos] = edge_src[i];
        return;
    }
    int q = bid - CNT_BLK;
    int z = q >> 6;
    int rem = q & 63;
    int by = rem >> 3, bx = rem & 7;
    int tx = threadIdx.x & 31, ty = threadIdx.x >> 5;
    const float* src;
    ushort* dst;
    int N;
    if (z < LL * RR) {
        src = W + (size_t)z * CDIM * CDIM;
        dst = Wt + (size_t)z * CDIM * CDIM;
        N = CDIM;
    } else {
        src = fc_w;
        dst = fct;
        N = OUTD;
    }
    int kb = bx * 32, nb = by * 32;
    if (nb >= N) return;
    for (int yy = ty; yy < 32; yy += 8)
        tile[yy][tx] = src[(size_t)(kb + yy) * N + nb + tx];
    __syncthreads();
    for (int yy = ty; yy < 32; yy += 8)
        dst[(size_t)(nb + yy) * CDIM + kb + tx] = f2bf(tile[tx][yy]);
}

// ---------------- bf16 MFMA GEMM (+ fused el/er epilogue) ----------------
// (round-0 proven version; do not restructure — r5's relation-folded variant
// lost 17 us/layer to the 1-wave/SIMD occupancy cliff from 192 acc VGPRs.)

#define TM 128
#define TN 128
#define TK 32

__global__ __launch_bounds__(256) void gemm_bf16(
    const ushort* __restrict__ A, const ushort* __restrict__ Bt0, void* __restrict__ C0,
    int M, int K, int Ncol, long strideB, long strideC,
    const float* __restrict__ bias, int out_fp32,
    const float* __restrict__ al_all, const float* __restrict__ ar_all,
    float* __restrict__ el_all, float* __restrict__ er_all) {
    __shared__ alignas(16) ushort As[TM * 32];
    __shared__ alignas(16) ushort Bs[TN * 32];
    const ushort* Bt = Bt0 + (size_t)blockIdx.z * strideB;
    int m0 = blockIdx.x * TM, n0 = blockIdx.y * TN;
    int t = threadIdx.x;
    int wave = t >> 6, lane = t & 63;
    int q = lane >> 4, l16 = lane & 15;
    int wrow = (wave >> 1) * 64, wcol = (wave & 1) * 64;

    int sw = (q ^ ((l16 >> 1) & 3)) * 8;
    int a_off[4], b_off[4];
    #pragma unroll
    for (int i = 0; i < 4; i++) {
        a_off[i] = (wrow + i * 16 + l16) * 32 + sw;
        b_off[i] = (wcol + i * 16 + l16) * 32 + sw;
    }
    int row_a = t >> 2;
    int ch_a  = ((t & 3) ^ ((row_a >> 1) & 3)) * 8;

    f32x4 acc[4][4];
    #pragma unroll
    for (int i = 0; i < 4; i++)
        #pragma unroll
        for (int j = 0; j < 4; j++)
            #pragma unroll
            for (int k = 0; k < 4; k++) acc[i][j][k] = 0.f;

    for (int k0 = 0; k0 < K; k0 += TK) {
        #pragma unroll
        for (int s = 0; s < 2; s++) {
            int qid = t + s * 256;
            int row = row_a + s * 64;
            glds16(A + (size_t)(m0 + row) * K + k0 + ch_a, As + qid * 8);
        }
        #pragma unroll
        for (int s = 0; s < 2; s++) {
            int qid = t + s * 256;
            int row = row_a + s * 64;
            glds16(Bt + (size_t)(n0 + row) * K + k0 + ch_a, Bs + qid * 8);
        }
        __syncthreads();
        sh8 af[4], bfr[4];
        #pragma unroll
        for (int i = 0; i < 4; i++) af[i] = *(const sh8*)(As + a_off[i]);
        #pragma unroll
        for (int j = 0; j < 4; j++) bfr[j] = *(const sh8*)(Bs + b_off[j]);
        #pragma unroll
        for (int i = 0; i < 4; i++)
            #pragma unroll
            for (int j = 0; j < 4; j++)
                acc[i][j] = __builtin_amdgcn_mfma_f32_16x16x32_bf16(af[i], bfr[j], acc[i][j], 0, 0, 0);
        __syncthreads();
    }

    if (out_fp32) {
        float* C = (float*)C0 + (size_t)blockIdx.z * strideC;
        #pragma unroll
        for (int i = 0; i < 4; i++) {
            #pragma unroll
            for (int reg = 0; reg < 4; reg++) {
                int row = m0 + wrow + i * 16 + q * 4 + reg;
                if (row >= M) continue;
                #pragma unroll
                for (int j = 0; j < 4; j++) {
                    int col = n0 + wcol + j * 16 + l16;
                    float v = acc[i][j][reg];
                    if (bias) v += bias[col];
                    C[(size_t)row * Ncol + col] = v;
                }
            }
        }
    } else {
        ushort* C = (ushort*)C0 + (size_t)blockIdx.z * strideC;
        #pragma unroll
        for (int i = 0; i < 4; i++) {
            #pragma unroll
            for (int reg = 0; reg < 4; reg++) {
                int row = m0 + wrow + i * 16 + q * 4 + reg;
                if (row >= M) continue;
                #pragma unroll
                for (int j = 0; j < 4; j++) {
                    int col = n0 + wcol + j * 16 + l16;
                    C[(size_t)row * Ncol + col] = f2bf(acc[i][j][reg]);
                }
            }
        }
    }

    if (el_all) {
        const float* al = al_all + (size_t)blockIdx.z * CDIM;
        const float* ar = ar_all + (size_t)blockIdx.z * CDIM;
        float* elp = el_all + (size_t)blockIdx.z * NN * HH;
        float* erp = er_all + (size_t)blockIdx.z * NN * HH;
        int head = (n0 + wcol) >> 6;
        float alj[4], arj[4];
        #pragma unroll
        for (int j = 0; j < 4; j++) {
            int gcol = n0 + wcol + j * 16 + l16;
            alj[j] = al[gcol];
            arj[j] = ar[gcol];
        }
        #pragma unroll
        for (int i = 0; i < 4; i++) {
            #pragma unroll
            for (int reg = 0; reg < 4; reg++) {
                int row = m0 + wrow + i * 16 + q * 4 + reg;
                float pl = 0.f, pr = 0.f;
                #pragma unroll
                for (int j = 0; j < 4; j++) {
                    pl = fmaf(acc[i][j][reg], alj[j], pl);
                    pr = fmaf(acc[i][j][reg], arj[j], pr);
                }
                #pragma unroll
                for (int m = 1; m < 16; m <<= 1) {
                    pl += __shfl_xor(pl, m, 64);
                    pr += __shfl_xor(pr, m, 64);
                }
                if (l16 == 0 && row < M) {
                    elp[(size_t)row * HH + head] = pl;
                    erp[(size_t)row * HH + head] = pr;
                }
            }
        }
    }
}

// ---------------- fused softmax + aggregation: half-wave edge-parity ----------------
// wave per node; lane = parity(2) x 32 channel-owners (8 ch = uint4 = 16 B).
// One uint4 load covers TWO edges per instruction (vs one 512B row per
// uint2 instr in r0): per-edge idx/el/exp/address work halves, fma count
// conserved, logical bytes identical. 8 edges per pass (4 feat loads in
// flight = 4 KB/wave, 2x r0) + one masked tail pass. Cross-half
// shfl_xor(32) folds parity partials once per relation. Targets the
// measured 41us VALU and the vmem-instruction-queue concurrency cap
// simultaneously; VGPR budget kept under the 64 cliff.
__global__ __launch_bounds__(256) void aggregate_fused(
    const ushort* __restrict__ feat16, const float* __restrict__ el,
    const float* __restrict__ er, const int* __restrict__ row_ptr,
    const int* __restrict__ csr_src, const float* __restrict__ bias,
    ushort* __restrict__ hout, int relu) {
    int wv = threadIdx.x >> 6, lane = threadIdx.x & 63;
    int node = blockIdx.x * 4 + wv;
    if (node >= NN) return;
    int half = lane >> 5;            // edge parity
    int l32 = lane & 31;
    int ch0 = l32 * 8;               // 8 ushort channels per lane
    int h = l32 >> 3;                // head = ch0/64
    float t[8];
    #pragma unroll
    for (int c = 0; c < 8; c++) t[c] = 0.f;

    #pragma unroll
    for (int r = 0; r < RR; r++) {
        const int* rp = row_ptr + r * (NN + 1);
        int beg = rp[node], end = rp[node + 1];
        const ushort* fr = feat16 + (size_t)r * NN * CDIM;
        const float* elr = el + (size_t)r * NN * HH;
        float ern = er[((size_t)r * NN + node) * HH + h];
        const int* cs = csr_src + (size_t)r * EE;
        float p[8];
        #pragma unroll
        for (int c = 0; c < 8; c++) p[c] = 0.f;
        float ssum = 0.f;
        int e = beg;
        // main: 8 edges per pass, this half-wave handles parity `half`
        for (; e + 8 <= end; e += 8) {
            uint s0 = (uint)cs[e + half];
            uint s1 = (uint)cs[e + 2 + half];
            uint s2 = (uint)cs[e + 4 + half];
            uint s3 = (uint)cs[e + 6 + half];
            float x0 = elr[(s0 << 2) + h];
            float x1 = elr[(s1 << 2) + h];
            float x2 = elr[(s2 << 2) + h];
            float x3 = elr[(s3 << 2) + h];
            uint4 f0 = *(const uint4*)(fr + (s0 << 8) + ch0);
            uint4 f1 = *(const uint4*)(fr + (s1 << 8) + ch0);
            uint4 f2 = *(const uint4*)(fr + (s2 << 8) + ch0);
            uint4 f3 = *(const uint4*)(fr + (s3 << 8) + ch0);
            x0 += ern; x1 += ern; x2 += ern; x3 += ern;
            x0 = x0 > 0.f ? x0 : NEG * x0;
            x1 = x1 > 0.f ? x1 : NEG * x1;
            x2 = x2 > 0.f ? x2 : NEG * x2;
            x3 = x3 > 0.f ? x3 : NEG * x3;
            float a0 = __expf(x0), a1 = __expf(x1), a2 = __expf(x2), a3 = __expf(x3);
            ssum += a0 + a1 + a2 + a3;
            p[0] = fmaf(a0, bflo(f0.x), p[0]); p[1] = fmaf(a0, bfhi(f0.x), p[1]);
            p[2] = fmaf(a0, bflo(f0.y), p[2]); p[3] = fmaf(a0, bfhi(f0.y), p[3]);
            p[4] = fmaf(a0, bflo(f0.z), p[4]); p[5] = fmaf(a0, bfhi(f0.z), p[5]);
            p[6] = fmaf(a0, bflo(f0.w), p[6]); p[7] = fmaf(a0, bfhi(f0.w), p[7]);
            p[0] = fmaf(a1, bflo(f1.x), p[0]); p[1] = fmaf(a1, bfhi(f1.x), p[1]);
            p[2] = fmaf(a1, bflo(f1.y), p[2]); p[3] = fmaf(a1, bfhi(f1.y), p[3]);
            p[4] = fmaf(a1, bflo(f1.z), p[4]); p[5] = fmaf(a1, bfhi(f1.z), p[5]);
            p[6] = fmaf(a1, bflo(f1.w), p[6]); p[7] = fmaf(a1, bfhi(f1.w), p[7]);
            p[0] = fmaf(a2, bflo(f2.x), p[0]); p[1] = fmaf(a2, bfhi(f2.x), p[1]);
            p[2] = fmaf(a2, bflo(f2.y), p[2]); p[3] = fmaf(a2, bfhi(f2.y), p[3]);
            p[4] = fmaf(a2, bflo(f2.z), p[4]); p[5] = fmaf(a2, bfhi(f2.z), p[5]);
            p[6] = fmaf(a2, bflo(f2.w), p[6]); p[7] = fmaf(a2, bfhi(f2.w), p[7]);
            p[0] = fmaf(a3, bflo(f3.x), p[0]); p[1] = fmaf(a3, bfhi(f3.x), p[1]);
            p[2] = fmaf(a3, bflo(f3.y), p[2]); p[3] = fmaf(a3, bfhi(f3.y), p[3]);
            p[4] = fmaf(a3, bflo(f3.z), p[4]); p[5] = fmaf(a3, bfhi(f3.z), p[5]);
            p[6] = fmaf(a3, bflo(f3.w), p[6]); p[7] = fmaf(a3, bfhi(f3.w), p[7]);
        }
        // masked tail pass (0-7 edges)
        if (e < end) {
            int last = end - 1;
            int j0 = e + half, j1 = e + 2 + half, j2 = e + 4 + half, j3 = e + 6 + half;
            bool m0 = j0 < end, m1 = j1 < end, m2 = j2 < end, m3 = j3 < end;
            uint s0 = (uint)cs[m0 ? j0 : last];
            uint s1 = (uint)cs[m1 ? j1 : last];
            uint s2 = (uint)cs[m2 ? j2 : last];
            uint s3 = (uint)cs[m3 ? j3 : last];
            float x0 = elr[(s0 << 2) + h];
            float x1 = elr[(s1 << 2) + h];
            float x2 = elr[(s2 << 2) + h];
            float x3 = elr[(s3 << 2) + h];
            uint4 f0 = *(const uint4*)(fr + (s0 << 8) + ch0);
            uint4 f1 = *(const uint4*)(fr + (s1 << 8) + ch0);
            uint4 f2 = *(const uint4*)(fr + (s2 << 8) + ch0);
            uint4 f3 = *(const uint4*)(fr + (s3 << 8) + ch0);
            x0 += ern; x1 += ern; x2 += ern; x3 += ern;
            x0 = x0 > 0.f ? x0 : NEG * x0;
            x1 = x1 > 0.f ? x1 : NEG * x1;
            x2 = x2 > 0.f ? x2 : NEG * x2;
            x3 = x3 > 0.f ? x3 : NEG * x3;
            float a0 = m0 ? __expf(x0) : 0.f;
            float a1 = m1 ? __expf(x1) : 0.f;
            float a2 = m2 ? __expf(x2) : 0.f;
            float a3 = m3 ? __expf(x3) : 0.f;
            ssum += a0 + a1 + a2 + a3;
            p[0] = fmaf(a0, bflo(f0.x), p[0]); p[1] = fmaf(a0, bfhi(f0.x), p[1]);
            p[2] = fmaf(a0, bflo(f0.y), p[2]); p[3] = fmaf(a0, bfhi(f0.y), p[3]);
            p[4] = fmaf(a0, bflo(f0.z), p[4]); p[5] = fmaf(a0, bfhi(f0.z), p[5]);
            p[6] = fmaf(a0, bflo(f0.w), p[6]); p[7] = fmaf(a0, bfhi(f0.w), p[7]);
            p[0] = fmaf(a1, bflo(f1.x), p[0]); p[1] = fmaf(a1, bfhi(f1.x), p[1]);
            p[2] = fmaf(a1, bflo(f1.y), p[2]); p[3] = fmaf(a1, bfhi(f1.y), p[3]);
            p[4] = fmaf(a1, bflo(f1.z), p[4]); p[5] = fmaf(a1, bfhi(f1.z), p[5]);
            p[6] = fmaf(a1, bflo(f1.w), p[6]); p[7] = fmaf(a1, bfhi(f1.w), p[7]);
            p[0] = fmaf(a2, bflo(f2.x), p[0]); p[1] = fmaf(a2, bfhi(f2.x), p[1]);
            p[2] = fmaf(a2, bflo(f2.y), p[2]); p[3] = fmaf(a2, bfhi(f2.y), p[3]);
            p[4] = fmaf(a2, bflo(f2.z), p[4]); p[5] = fmaf(a2, bfhi(f2.z), p[5]);
            p[6] = fmaf(a2, bflo(f2.w), p[6]); p[7] = fmaf(a2, bfhi(f2.w), p[7]);
            p[0] = fmaf(a3, bflo(f3.x), p[0]); p[1] = fmaf(a3, bfhi(f3.x), p[1]);
            p[2] = fmaf(a3, bflo(f3.y), p[2]); p[3] = fmaf(a3, bfhi(f3.y), p[3]);
            p[4] = fmaf(a3, bflo(f3.z), p[4]); p[5] = fmaf(a3, bfhi(f3.z), p[5]);
            p[6] = fmaf(a3, bflo(f3.w), p[6]); p[7] = fmaf(a3, bfhi(f3.w), p[7]);
        }
        // fold the two parity halves; normalize; accumulate with bias
        ssum += __shfl_xor(ssum, 32, 64);
        float is = (end > beg) ? 1.f / ssum : 0.f;
        #pragma unroll
        for (int c = 0; c < 8; c++) {
            float pc = p[c] + __shfl_xor(p[c], 32, 64);
            t[c] = fmaf(pc, is, t[c]);
        }
        #pragma unroll
        for (int c = 0; c < 8; c += 2) {
            float2 b = *(const float2*)(bias + r * CDIM + ch0 + c);
            t[c] += b.x; t[c + 1] += b.y;
        }
    }
    if (relu) {
        #pragma unroll
        for (int c = 0; c < 8; c++) t[c] = fmaxf(t[c], 0.f);
    }
    if (half == 0) {
        uint4 o;
        o.x = (uint)f2bf(t[0]) | ((uint)f2bf(t[1]) << 16);
        o.y = (uint)f2bf(t[2]) | ((uint)f2bf(t[3]) << 16);
        o.z = (uint)f2bf(t[4]) | ((uint)f2bf(t[5]) << 16);
        o.w = (uint)f2bf(t[6]) | ((uint)f2bf(t[7]) << 16);
        *(uint4*)(hout + (size_t)node * CDIM + ch0) = o;
    }
}

// ---------------- launcher ----------------

extern "C" void kernel_launch(void* const* d_in, const int* in_sizes, int n_in,
                              void* d_out, int out_size, void* d_ws, size_t ws_size,
                              hipStream_t stream) {
    const float* x        = (const float*)d_in[0];
    const int*   edge_src = (const int*)d_in[1];
    const int*   edge_dst = (const int*)d_in[2];
    const float* W        = (const float*)d_in[3];
    const float* attn_l   = (const float*)d_in[4];
    const float* attn_r   = (const float*)d_in[5];
    const float* bias     = (const float*)d_in[6];
    const float* fc_w     = (const float*)d_in[7];
    const float* fc_b     = (const float*)d_in[8];
    float* out = (float*)d_out;

    char* ws = (char*)d_ws;
    size_t off = 0;
    auto alloc = [&](size_t bytes) {
        void* p = ws + off;
        off = (off + bytes + 255) & ~(size_t)255;
        return p;
    };
    ushort* x16    = (ushort*)alloc((size_t)NN_PAD * CDIM * 2);  // padded: glds A-source
    ushort* h16    = (ushort*)alloc((size_t)NN_PAD * CDIM * 2);  // padded: glds A-source
    ushort* feat16 = (ushort*)alloc((size_t)RR * NN * CDIM * 2);
    ushort* Wt16   = (ushort*)alloc((size_t)LL * RR * CDIM * CDIM * 2);
    ushort* fct16  = (ushort*)alloc((size_t)OUTD * CDIM * 2);
    float* el      = (float*)alloc((size_t)RR * NN * HH * 4);
    float* er      = (float*)alloc((size_t)RR * NN * HH * 4);
    int* row_ptr   = (int*)alloc((size_t)RR * (NN + 1) * 4);
    int* cursor    = (int*)alloc((size_t)RR * (NN + 1) * 4);
    int* csr_src   = (int*)alloc((size_t)RR * EE * 4);
    int* deg       = (int*)alloc((size_t)RR * NN * 4);

    // prologue: memset -> [cvt || count] -> scan -> [fill || prep]
    hipMemsetAsync(deg, 0, (size_t)RR * NN * 4, stream);
    fused_cvt_count<<<dim3(CVT_BLK + CNT_BLK), dim3(256), 0, stream>>>(
        x, x16, edge_dst, deg);
    scan_kernel<<<dim3(RR), dim3(1024), 0, stream>>>(deg, row_ptr, cursor);
    fused_fill_prep<<<dim3(CNT_BLK + PREP_BLK), dim3(256), 0, stream>>>(
        edge_src, edge_dst, cursor, csr_src, W, fc_w, Wt16, fct16);

    const ushort* hin = x16;
    for (int l = 0; l < LL; l++) {
        const ushort* Wl = Wt16 + (size_t)l * RR * CDIM * CDIM;
        dim3 g(NN_PAD / TM, CDIM / TN, RR);
        gemm_bf16<<<g, dim3(256), 0, stream>>>(hin, Wl, feat16, NN, CDIM, CDIM,
                                               (long)CDIM * CDIM, (long)NN * CDIM, nullptr, 0,
                                               attn_l + (size_t)l * RR * CDIM,
                                               attn_r + (size_t)l * RR * CDIM, el, er);
        aggregate_fused<<<dim3(NN / 4), dim3(256), 0, stream>>>(
            feat16, el, er, row_ptr, csr_src, bias + (size_t)l * RR * CDIM,
            h16, (l != LL - 1) ? 1 : 0);
        hin = h16;
    }
    dim3 gf(NN_PAD / TM, OUTD / TN, 1);
    gemm_bf16<<<gf, dim3(256), 0, stream>>>(h16, fct16, out, NN, CDIM, OUTD,
                                            0, 0, fc_b, 1, nullptr, nullptr, nullptr, nullptr);
}

// Round 8
// 508.251 us; speedup vs baseline: 1.0124x; 1.0124x over previous
//
#include <hip/hip_runtime.h>
#include <math.h>

#define NN 20000
#define NN_PAD 20096   // NN rounded up to TM; pad rows are garbage, never stored
#define EE 320000
#define RR 3
#define LL 3
#define HH 4
#define DD 64
#define CDIM 256   // H*D == IN
#define OUTD 128
#define NEG 0.2f

#define CVT_N4 (NN * CDIM / 4)             // 1,280,000 float4 groups
#define CVT_BLK ((CVT_N4 + 255) / 256)     // 5000
#define CNT_BLK ((RR * EE + 255) / 256)    // 3750
#define PREP_BLK (8 * 8 * (LL * RR + 1))   // 640

typedef float f32x4 __attribute__((ext_vector_type(4)));
typedef short sh8 __attribute__((ext_vector_type(8)));

__device__ __forceinline__ ushort f2bf(float f) {
    union { float f; uint u; } v; v.f = f;
    uint r = (v.u + 0x7FFF + ((v.u >> 16) & 1)) >> 16;   // RNE
    return (ushort)r;
}
__device__ __forceinline__ float bf2f(ushort u) {
    union { uint u; float f; } v; v.u = ((uint)u) << 16;
    return v.f;
}
__device__ __forceinline__ float bflo(uint p) { return bf2f((ushort)(p & 0xffff)); }
__device__ __forceinline__ float bfhi(uint p) { return bf2f((ushort)(p >> 16)); }

// async global->LDS, 16 B per lane; LDS dst is wave-uniform base + lane*16
__device__ __forceinline__ void glds16(const ushort* g, ushort* l) {
    __builtin_amdgcn_global_load_lds(
        (const __attribute__((address_space(1))) void*)g,
        (__attribute__((address_space(3))) void*)l, 16, 0, 0);
}

// ---------------- fused prologue 1: x->bf16 cvt  ||  degree count ----------------
__global__ __launch_bounds__(256) void fused_cvt_count(
    const float* __restrict__ in, ushort* __restrict__ out,
    const int* __restrict__ edge_dst, int* __restrict__ deg) {
    int bid = blockIdx.x;
    if (bid < CVT_BLK) {
        int i = bid * 256 + threadIdx.x;
        if (i >= CVT_N4) return;
        float4 v = *(const float4*)(in + (size_t)i * 4);
        ushort4 o;
        o.x = f2bf(v.x); o.y = f2bf(v.y); o.z = f2bf(v.z); o.w = f2bf(v.w);
        *(ushort4*)(out + (size_t)i * 4) = o;
    } else {
        int i = (bid - CVT_BLK) * 256 + threadIdx.x;
        if (i >= RR * EE) return;
        int r = i / EE;
        atomicAdd(&deg[r * NN + edge_dst[i]], 1);
    }
}

// one block per relation; wave-shfl scan; writes row_ptr AND cursor copy.
__global__ __launch_bounds__(1024) void scan_kernel(
    const int* __restrict__ deg, int* __restrict__ row_ptr, int* __restrict__ cursor) {
    int r = blockIdx.x;
    const int* d = deg + r * NN;
    int* rp = row_ptr + r * (NN + 1);
    int* cur = cursor + r * (NN + 1);
    __shared__ int wsum[16];
    int lane = threadIdx.x & 63, wv = threadIdx.x >> 6;
    if (threadIdx.x == 0) { rp[0] = 0; cur[0] = 0; }
    int carry = 0;
    for (int base = 0; base < NN; base += 1024) {
        int i = base + threadIdx.x;
        int v = (i < NN) ? d[i] : 0;
        int s = v;
        #pragma unroll
        for (int off = 1; off < 64; off <<= 1) {
            int n = __shfl_up(s, off, 64);
            if (lane >= off) s += n;
        }
        if (lane == 63) wsum[wv] = s;
        __syncthreads();
        if (wv == 0) {
            int ws = (lane < 16) ? wsum[lane] : 0;
            #pragma unroll
            for (int off = 1; off < 16; off <<= 1) {
                int n = __shfl_up(ws, off, 64);
                if (lane >= off) ws += n;
            }
            if (lane < 16) wsum[lane] = ws;
        }
        __syncthreads();
        int incl = carry + (wv ? wsum[wv - 1] : 0) + s;
        if (i < NN) { rp[i + 1] = incl; cur[i + 1] = incl; }
        carry += wsum[15];
        __syncthreads();
    }
}

// ---------------- fused prologue 2: CSR fill  ||  weight transpose prep ----------------
__global__ __launch_bounds__(256) void fused_fill_prep(
    const int* __restrict__ edge_src, const int* __restrict__ edge_dst,
    int* __restrict__ cursor, int* __restrict__ csr_src,
    const float* __restrict__ W, const float* __restrict__ fc_w,
    ushort* __restrict__ Wt, ushort* __restrict__ fct) {
    __shared__ float tile[32][33];
    int bid = blockIdx.x;
    if (bid < CNT_BLK) {
        int i = bid * 256 + threadIdx.x;
        if (i >= RR * EE) return;
        int r = i / EE;
        int dst = edge_dst[i];
        int pos = atomicAdd(&cursor[r * (NN + 1) + dst], 1);
        csr_src[r * EE + pos] = edge_src[i];
        return;
    }
    int q = bid - CNT_BLK;
    int z = q >> 6;
    int rem = q & 63;
    int by = rem >> 3, bx = rem & 7;
    int tx = threadIdx.x & 31, ty = threadIdx.x >> 5;
    const float* src;
    ushort* dst;
    int N;
    if (z < LL * RR) {
        src = W + (size_t)z * CDIM * CDIM;
        dst = Wt + (size_t)z * CDIM * CDIM;
        N = CDIM;
    } else {
        src = fc_w;
        dst = fct;
        N = OUTD;
    }
    int kb = bx * 32, nb = by * 32;
    if (nb >= N) return;
    for (int yy = ty; yy < 32; yy += 8)
        tile[yy][tx] = src[(size_t)(kb + yy) * N + nb + tx];
    __syncthreads();
    for (int yy = ty; yy < 32; yy += 8)
        dst[(size_t)(nb + yy) * CDIM + kb + tx] = f2bf(tile[tx][yy]);
}

// ---------------- bf16 MFMA GEMM (+ fused el/er epilogue) ----------------
// C[M][Ncol] = A[M][K](bf16) @ Bt[Ncol][K](bf16)^T ; 128x128 tile, BK=64.
// TK 32->64 (r8): A re-reads are L2/L3-resident (A is 10.3 MB, L3 256 MB),
// so the GEMM is barrier-drain-bound, not HBM-bound -- halving the number
// of vmcnt(0)+barrier pairs (8->4 per block; 32 MFMA per drain) attacks the
// known stall directly. LDS 32 KB (two concatenated 32-k halves so all
// r0-proven offset math is reused); acc footprint unchanged (r5's relation-
// folded variant died by tripling acc VGPRs -- this does not).

#define TM 128
#define TN 128
#define TK 64

__global__ __launch_bounds__(256) void gemm_bf16(
    const ushort* __restrict__ A, const ushort* __restrict__ Bt0, void* __restrict__ C0,
    int M, int K, int Ncol, long strideB, long strideC,
    const float* __restrict__ bias, int out_fp32,
    const float* __restrict__ al_all, const float* __restrict__ ar_all,
    float* __restrict__ el_all, float* __restrict__ er_all) {
    __shared__ alignas(16) ushort As[2 * TM * 32];
    __shared__ alignas(16) ushort Bs[2 * TN * 32];
    const ushort* Bt = Bt0 + (size_t)blockIdx.z * strideB;
    int m0 = blockIdx.x * TM, n0 = blockIdx.y * TN;
    int t = threadIdx.x;
    int wave = t >> 6, lane = t & 63;
    int q = lane >> 4, l16 = lane & 15;
    int wrow = (wave >> 1) * 64, wcol = (wave & 1) * 64;

    // fragment LDS offsets (shorts), k0-independent; chunk swizzle = q ^ ((l16>>1)&3)
    int sw = (q ^ ((l16 >> 1) & 3)) * 8;
    int a_off[4], b_off[4];
    #pragma unroll
    for (int i = 0; i < 4; i++) {
        a_off[i] = (wrow + i * 16 + l16) * 32 + sw;
        b_off[i] = (wcol + i * 16 + l16) * 32 + sw;
    }
    // staging: qid in [0,512): row = qid>>2, global chunk = (qid&3) ^ ((row>>1)&3)
    int row_a = t >> 2;
    int ch_a  = ((t & 3) ^ ((row_a >> 1) & 3)) * 8;

    f32x4 acc[4][4];
    #pragma unroll
    for (int i = 0; i < 4; i++)
        #pragma unroll
        for (int j = 0; j < 4; j++)
            #pragma unroll
            for (int k = 0; k < 4; k++) acc[i][j][k] = 0.f;

    for (int k0 = 0; k0 < K; k0 += TK) {
        #pragma unroll
        for (int hf = 0; hf < 2; hf++)
            #pragma unroll
            for (int s = 0; s < 2; s++) {
                int qid = t + s * 256;
                int row = row_a + s * 64;
                glds16(A + (size_t)(m0 + row) * K + k0 + hf * 32 + ch_a,
                       As + hf * (TM * 32) + qid * 8);
            }
        #pragma unroll
        for (int hf = 0; hf < 2; hf++)
            #pragma unroll
            for (int s = 0; s < 2; s++) {
                int qid = t + s * 256;
                int row = row_a + s * 64;
                glds16(Bt + (size_t)(n0 + row) * K + k0 + hf * 32 + ch_a,
                       Bs + hf * (TN * 32) + qid * 8);
            }
        __syncthreads();
        #pragma unroll
        for (int hf = 0; hf < 2; hf++) {
            sh8 af[4], bfr[4];
            #pragma unroll
            for (int i = 0; i < 4; i++) af[i] = *(const sh8*)(As + hf * (TM * 32) + a_off[i]);
            #pragma unroll
            for (int j = 0; j < 4; j++) bfr[j] = *(const sh8*)(Bs + hf * (TN * 32) + b_off[j]);
            #pragma unroll
            for (int i = 0; i < 4; i++)
                #pragma unroll
                for (int j = 0; j < 4; j++)
                    acc[i][j] = __builtin_amdgcn_mfma_f32_16x16x32_bf16(af[i], bfr[j], acc[i][j], 0, 0, 0);
        }
        __syncthreads();
    }

    // epilogue: C/D layout col=lane&15, row=q*4+reg
    if (out_fp32) {
        float* C = (float*)C0 + (size_t)blockIdx.z * strideC;
        #pragma unroll
        for (int i = 0; i < 4; i++) {
            #pragma unroll
            for (int reg = 0; reg < 4; reg++) {
                int row = m0 + wrow + i * 16 + q * 4 + reg;
                if (row >= M) continue;
                #pragma unroll
                for (int j = 0; j < 4; j++) {
                    int col = n0 + wcol + j * 16 + l16;
                    float v = acc[i][j][reg];
                    if (bias) v += bias[col];
                    C[(size_t)row * Ncol + col] = v;
                }
            }
        }
    } else {
        ushort* C = (ushort*)C0 + (size_t)blockIdx.z * strideC;
        #pragma unroll
        for (int i = 0; i < 4; i++) {
            #pragma unroll
            for (int reg = 0; reg < 4; reg++) {
                int row = m0 + wrow + i * 16 + q * 4 + reg;
                if (row >= M) continue;
                #pragma unroll
                for (int j = 0; j < 4; j++) {
                    int col = n0 + wcol + j * 16 + l16;
                    C[(size_t)row * Ncol + col] = f2bf(acc[i][j][reg]);
                }
            }
        }
    }

    if (el_all) {
        const float* al = al_all + (size_t)blockIdx.z * CDIM;
        const float* ar = ar_all + (size_t)blockIdx.z * CDIM;
        float* elp = el_all + (size_t)blockIdx.z * NN * HH;
        float* erp = er_all + (size_t)blockIdx.z * NN * HH;
        int head = (n0 + wcol) >> 6;
        float alj[4], arj[4];
        #pragma unroll
        for (int j = 0; j < 4; j++) {
            int gcol = n0 + wcol + j * 16 + l16;
            alj[j] = al[gcol];
            arj[j] = ar[gcol];
        }
        #pragma unroll
        for (int i = 0; i < 4; i++) {
            #pragma unroll
            for (int reg = 0; reg < 4; reg++) {
                int row = m0 + wrow + i * 16 + q * 4 + reg;
                float pl = 0.f, pr = 0.f;
                #pragma unroll
                for (int j = 0; j < 4; j++) {
                    pl = fmaf(acc[i][j][reg], alj[j], pl);
                    pr = fmaf(acc[i][j][reg], arj[j], pr);
                }
                #pragma unroll
                for (int m = 1; m < 16; m <<= 1) {
                    pl += __shfl_xor(pl, m, 64);
                    pr += __shfl_xor(pr, m, 64);
                }
                if (l16 == 0 && row < M) {
                    elp[(size_t)row * HH + head] = pl;
                    erp[(size_t)row * HH + head] = pr;
                }
            }
        }
    }
}

// ---------------- fused softmax + aggregation (round-0 proven config) ----------------
// wave per node (4 nodes/block); lane owns 4 channels (one uint2 = 8 B).
// 4-edge software pipeline; per-lane redundant exp (free on SIMD); scalar
// el gather (4B, 16-lane HW broadcast per head group). CLOSED at ~73 us:
// compulsory fetch = 218 MB (8-XCD duplication of the 30.7 MB feat table;
// every XCD touches ~99.8% of rows, so no layout fixes it) at the ~3.3 TB/s
// random-gather fill ceiling (r7 proved fill is NOT wave-concurrency-bound:
// occupancy halved, BW rose). r3 chunking=173us, r4 pipeline=79.9us,
// r7 half-wave=74.3us. Do not touch.
__global__ __launch_bounds__(256) void aggregate_fused(
    const ushort* __restrict__ feat16, const float* __restrict__ el,
    const float* __restrict__ er, const int* __restrict__ row_ptr,
    const int* __restrict__ csr_src, const float* __restrict__ bias,
    ushort* __restrict__ hout, int relu) {
    int wv = threadIdx.x >> 6, lane = threadIdx.x & 63;
    int node = blockIdx.x * 4 + wv;
    if (node >= NN) return;
    int c0 = lane * 4;
    int h = lane >> 4;
    float t0 = 0.f, t1 = 0.f, t2 = 0.f, t3 = 0.f;
    #pragma unroll
    for (int r = 0; r < RR; r++) {
        const int* rp = row_ptr + r * (NN + 1);
        int beg = rp[node], end = rp[node + 1];
        const ushort* fr = feat16 + (size_t)r * NN * CDIM;
        const float* elr = el + (size_t)r * NN * HH;
        float ern = er[((size_t)r * NN + node) * HH + h];
        const int* cs = csr_src + (size_t)r * EE;
        float p0 = 0.f, p1 = 0.f, p2 = 0.f, p3 = 0.f, ssum = 0.f;
        int e = beg;
        for (; e + 4 <= end; e += 4) {
            int s0 = cs[e], s1 = cs[e + 1], s2 = cs[e + 2], s3 = cs[e + 3];
            float x0 = elr[s0 * HH + h];
            float x1 = elr[s1 * HH + h];
            float x2 = elr[s2 * HH + h];
            float x3 = elr[s3 * HH + h];
            uint2 f0 = *(const uint2*)(fr + (size_t)s0 * CDIM + c0);
            uint2 f1 = *(const uint2*)(fr + (size_t)s1 * CDIM + c0);
            uint2 f2 = *(const uint2*)(fr + (size_t)s2 * CDIM + c0);
            uint2 f3 = *(const uint2*)(fr + (size_t)s3 * CDIM + c0);
            x0 += ern; x1 += ern; x2 += ern; x3 += ern;
            x0 = x0 > 0.f ? x0 : NEG * x0;
            x1 = x1 > 0.f ? x1 : NEG * x1;
            x2 = x2 > 0.f ? x2 : NEG * x2;
            x3 = x3 > 0.f ? x3 : NEG * x3;
            float a0 = __expf(x0), a1 = __expf(x1), a2 = __expf(x2), a3 = __expf(x3);
            ssum += a0 + a1 + a2 + a3;
            p0 = fmaf(a0, bflo(f0.x), p0); p1 = fmaf(a0, bfhi(f0.x), p1);
            p2 = fmaf(a0, bflo(f0.y), p2); p3 = fmaf(a0, bfhi(f0.y), p3);
            p0 = fmaf(a1, bflo(f1.x), p0); p1 = fmaf(a1, bfhi(f1.x), p1);
            p2 = fmaf(a1, bflo(f1.y), p2); p3 = fmaf(a1, bfhi(f1.y), p3);
            p0 = fmaf(a2, bflo(f2.x), p0); p1 = fmaf(a2, bfhi(f2.x), p1);
            p2 = fmaf(a2, bflo(f2.y), p2); p3 = fmaf(a2, bfhi(f2.y), p3);
            p0 = fmaf(a3, bflo(f3.x), p0); p1 = fmaf(a3, bfhi(f3.x), p1);
            p2 = fmaf(a3, bflo(f3.y), p2); p3 = fmaf(a3, bfhi(f3.y), p3);
        }
        for (; e < end; e++) {
            int s = cs[e];
            float x = elr[s * HH + h] + ern;
            x = x > 0.f ? x : NEG * x;
            float a = __expf(x);
            uint2 f = *(const uint2*)(fr + (size_t)s * CDIM + c0);
            ssum += a;
            p0 = fmaf(a, bflo(f.x), p0); p1 = fmaf(a, bfhi(f.x), p1);
            p2 = fmaf(a, bflo(f.y), p2); p3 = fmaf(a, bfhi(f.y), p3);
        }
        float is = (end > beg) ? 1.f / ssum : 0.f;
        t0 += p0 * is + bias[r * CDIM + c0];
        t1 += p1 * is + bias[r * CDIM + c0 + 1];
        t2 += p2 * is + bias[r * CDIM + c0 + 2];
        t3 += p3 * is + bias[r * CDIM + c0 + 3];
    }
    if (relu) {
        t0 = fmaxf(t0, 0.f); t1 = fmaxf(t1, 0.f);
        t2 = fmaxf(t2, 0.f); t3 = fmaxf(t3, 0.f);
    }
    uint2 o;
    o.x = (uint)f2bf(t0) | ((uint)f2bf(t1) << 16);
    o.y = (uint)f2bf(t2) | ((uint)f2bf(t3) << 16);
    *(uint2*)(hout + (size_t)node * CDIM + c0) = o;
}

// ---------------- launcher ----------------

extern "C" void kernel_launch(void* const* d_in, const int* in_sizes, int n_in,
                              void* d_out, int out_size, void* d_ws, size_t ws_size,
                              hipStream_t stream) {
    const float* x        = (const float*)d_in[0];
    const int*   edge_src = (const int*)d_in[1];
    const int*   edge_dst = (const int*)d_in[2];
    const float* W        = (const float*)d_in[3];
    const float* attn_l   = (const float*)d_in[4];
    const float* attn_r   = (const float*)d_in[5];
    const float* bias     = (const float*)d_in[6];
    const float* fc_w     = (const float*)d_in[7];
    const float* fc_b     = (const float*)d_in[8];
    float* out = (float*)d_out;

    char* ws = (char*)d_ws;
    size_t off = 0;
    auto alloc = [&](size_t bytes) {
        void* p = ws + off;
        off = (off + bytes + 255) & ~(size_t)255;
        return p;
    };
    ushort* x16    = (ushort*)alloc((size_t)NN_PAD * CDIM * 2);  // padded: glds A-source
    ushort* h16    = (ushort*)alloc((size_t)NN_PAD * CDIM * 2);  // padded: glds A-source
    ushort* feat16 = (ushort*)alloc((size_t)RR * NN * CDIM * 2);
    ushort* Wt16   = (ushort*)alloc((size_t)LL * RR * CDIM * CDIM * 2);
    ushort* fct16  = (ushort*)alloc((size_t)OUTD * CDIM * 2);
    float* el      = (float*)alloc((size_t)RR * NN * HH * 4);
    float* er      = (float*)alloc((size_t)RR * NN * HH * 4);
    int* row_ptr   = (int*)alloc((size_t)RR * (NN + 1) * 4);
    int* cursor    = (int*)alloc((size_t)RR * (NN + 1) * 4);
    int* csr_src   = (int*)alloc((size_t)RR * EE * 4);
    int* deg       = (int*)alloc((size_t)RR * NN * 4);

    // prologue: memset -> [cvt || count] -> scan -> [fill || prep]
    hipMemsetAsync(deg, 0, (size_t)RR * NN * 4, stream);
    fused_cvt_count<<<dim3(CVT_BLK + CNT_BLK), dim3(256), 0, stream>>>(
        x, x16, edge_dst, deg);
    scan_kernel<<<dim3(RR), dim3(1024), 0, stream>>>(deg, row_ptr, cursor);
    fused_fill_prep<<<dim3(CNT_BLK + PREP_BLK), dim3(256), 0, stream>>>(
        edge_src, edge_dst, cursor, csr_src, W, fc_w, Wt16, fct16);

    const ushort* hin = x16;
    for (int l = 0; l < LL; l++) {
        const ushort* Wl = Wt16 + (size_t)l * RR * CDIM * CDIM;
        dim3 g(NN_PAD / TM, CDIM / TN, RR);
        gemm_bf16<<<g, dim3(256), 0, stream>>>(hin, Wl, feat16, NN, CDIM, CDIM,
                                               (long)CDIM * CDIM, (long)NN * CDIM, nullptr, 0,
                                               attn_l + (size_t)l * RR * CDIM,
                                               attn_r + (size_t)l * RR * CDIM, el, er);
        aggregate_fused<<<dim3(NN / 4), dim3(256), 0, stream>>>(
            feat16, el, er, row_ptr, csr_src, bias + (size_t)l * RR * CDIM,
            h16, (l != LL - 1) ? 1 : 0);
        hin = h16;
    }
    dim3 gf(NN_PAD / TM, OUTD / TN, 1);
    gemm_bf16<<<gf, dim3(256), 0, stream>>>(h16, fct16, out, NN, CDIM, OUTD,
                                            0, 0, fc_b, 1, nullptr, nullptr, nullptr, nullptr);
}